// Round 2
// baseline (406.604 us; speedup 1.0000x reference)
//
#include <hip/hip_runtime.h>
#include <hip/hip_bf16.h>
#include <hip/hip_fp16.h>

#define N_NODES 100000
#define N_EDGES 1600000
#define IN_DIM 256
#define HIDDEN 128
#define NCLS 40
#define NCLS_PAD 48      // padded to 3 MFMA n-tiles

#define N_BUCKETS 256
#define NPB 391          // nodes per bucket = ceil(100000/256)
#define BCAP 8192        // bucket capacity (mean 6256, +24 sigma)
#define EPT 16           // edges per thread in bin phase
#define BIN_WG 4096      // edges per workgroup (256*16)
#define BIN_BLOCKS 391   // ceil(N_EDGES / BIN_WG)
#define GEMM1_BLOCKS 782 // ceil(N_NODES / 128)

typedef __attribute__((ext_vector_type(8))) _Float16 half8;
typedef __attribute__((ext_vector_type(4))) _Float16 half4f;
typedef __attribute__((ext_vector_type(4))) float floatx4;

// ---------------- k_prep: W1T / W2T fp16 transposes + bfill/deg zero ----------------

__global__ __launch_bounds__(256) void k_prep(const float* __restrict__ W1, __half* __restrict__ W1T,
                                              const float* __restrict__ W2, __half* __restrict__ W2T,
                                              int* __restrict__ bfill, int* __restrict__ deg) {
    const int t = threadIdx.x;
    if (blockIdx.x < 128) {              // W1T: [n][k] fp16, 128 x 256
        int i = blockIdx.x * 256 + t;
        int k = i >> 7, n = i & 127;
        W1T[n * IN_DIM + k] = __float2half_rn(W1[i]);
    } else if (blockIdx.x == 128) {      // W2T: [n][k] fp16, 48 x 128, zero-pad n>=40
        for (int i = t; i < NCLS_PAD * HIDDEN; i += 256) {
            int n = i >> 7, k = i & 127;
            W2T[n * HIDDEN + k] = (n < NCLS) ? __float2half_rn(W2[k * NCLS + n]) : __float2half_rn(0.f);
        }
    } else if (blockIdx.x == 129) {
        bfill[t] = 0;
    } else {                              // blocks 130..520: zero deg[100000]
        int i = (blockIdx.x - 130) * 256 + t;
        if (i < N_NODES) deg[i] = 0;
    }
}

// ---------------- k_deg: degree histogram (dst only), 8 edges/thread ----------------

__global__ __launch_bounds__(256) void k_deg(const int* __restrict__ dst, int* __restrict__ deg) {
    long e = (long)blockIdx.x * 2048 + threadIdx.x;
    #pragma unroll
    for (int i = 0; i < 8; i++, e += 256)
        if (e < N_EDGES) atomicAdd(&deg[dst[e]], 1);
}

// ---------------- k_dinv: dinv = rsqrt(deg + 1) ----------------

__global__ __launch_bounds__(256) void k_dinv(const int* __restrict__ deg, float* __restrict__ dinv) {
    int i = blockIdx.x * 256 + threadIdx.x;
    if (i < N_NODES) dinv[i] = rsqrtf((float)(deg[i] + 1));
}

// ---------------- k_binmm: [0,391) LDS-staged edge binning  ∥  [391,1173) GEMM1 (dinv-scaled write) ----------------

__global__ __launch_bounds__(256) void k_binmm(const int* __restrict__ src, const int* __restrict__ dst,
                                               int* __restrict__ bfill,
                                               unsigned long long* __restrict__ bpair,
                                               const float* __restrict__ X,
                                               const __half* __restrict__ W1T,
                                               const float* __restrict__ dinv,
                                               __half* __restrict__ H1s) {
    __shared__ __align__(16) char smraw[39936];   // union: bin(39936) / gemm1(36864)
    const int t = threadIdx.x;

    if (blockIdx.x < BIN_BLOCKS) {
        // ---- bin phase ----
        int* hist   = (int*)smraw;                               // 256
        int* bstart = hist + 256;                                // 256
        int* gbase  = bstart + 256;                              // 256
        unsigned long long* stage = (unsigned long long*)(smraw + 3072);   // 4096 (32 KB)
        unsigned char* bid = (unsigned char*)(smraw + 3072 + 32768);       // 4096
        hist[t] = 0;
        __syncthreads();
        const long e0 = (long)blockIdx.x * BIN_WG;
        const int n_valid = (int)min((long)BIN_WG, (long)N_EDGES - e0);
        int msrc[EPT], mdst[EPT], moff[EPT];
        #pragma unroll
        for (int i = 0; i < EPT; i++) {
            long e = e0 + t + i * 256;
            if (e < N_EDGES) {
                msrc[i] = src[e];
                mdst[i] = dst[e];
                moff[i] = atomicAdd(&hist[mdst[i] / NPB], 1);
            } else {
                mdst[i] = -1;
            }
        }
        __syncthreads();
        if (t < 64) {   // wave 0: exclusive scan of hist[256]
            int carry = 0;
            #pragma unroll
            for (int c = 0; c < 4; c++) {
                int idx = c * 64 + t;
                int hv = hist[idx];
                int s = hv;
                #pragma unroll
                for (int d2 = 1; d2 < 64; d2 <<= 1) {
                    int u = __shfl_up(s, d2, 64);
                    if (t >= d2) s += u;
                }
                bstart[idx] = carry + (s - hv);
                carry += __shfl(s, 63, 64);
            }
        }
        __syncthreads();
        int h = hist[t];
        gbase[t] = (h > 0) ? atomicAdd(&bfill[t], h) : 0;
        #pragma unroll
        for (int i = 0; i < EPT; i++) {
            if (mdst[i] >= 0) {
                int b = mdst[i] / NPB;
                int pos = bstart[b] + moff[i];
                stage[pos] = ((unsigned long long)(unsigned)mdst[i] << 32) | (unsigned)msrc[i];
                bid[pos] = (unsigned char)b;
            }
        }
        __syncthreads();
        for (int i = t; i < n_valid; i += 256) {
            int b = bid[i];
            int dest = gbase[b] + (i - bstart[b]);
            bpair[(long)b * BCAP + dest] = stage[i];
        }
        return;
    }

    // ---- gemm1 phase (128x128 tile, MFMA f16, dinv[row]-scaled output) ----
    _Float16 (*Asm)[72] = (_Float16(*)[72])smraw;
    _Float16 (*Bsm)[72] = (_Float16(*)[72])(smraw + 128 * 72 * 2);
    const int wave = t >> 6;
    const int lane = t & 63;
    const int m16  = lane & 15;
    const int kq   = lane >> 4;
    const int row0 = (blockIdx.x - BIN_BLOCKS) * 128;

    floatx4 acc[2][8];
    #pragma unroll
    for (int mt = 0; mt < 2; mt++)
        #pragma unroll
        for (int i = 0; i < 8; i++) acc[mt][i] = (floatx4)0.f;

    for (int kc = 0; kc < 4; kc++) {
        #pragma unroll
        for (int it = 0; it < 4; it++) {
            int u = t + it * 256;
            int r = u >> 3, j = u & 7;
            int gr = row0 + r;
            float4 x0 = make_float4(0.f, 0.f, 0.f, 0.f), x1 = x0;
            if (gr < N_NODES) {
                const float* p = &X[(long)gr * IN_DIM + kc * 64 + j * 8];
                x0 = *(const float4*)p;
                x1 = *(const float4*)(p + 4);
            }
            half8 hh;
            hh[0] = (_Float16)x0.x; hh[1] = (_Float16)x0.y; hh[2] = (_Float16)x0.z; hh[3] = (_Float16)x0.w;
            hh[4] = (_Float16)x1.x; hh[5] = (_Float16)x1.y; hh[6] = (_Float16)x1.z; hh[7] = (_Float16)x1.w;
            *(half8*)&Asm[r][j * 8] = hh;
        }
        #pragma unroll
        for (int it = 0; it < 4; it++) {
            int u = t + it * 256;
            int n = u >> 3, j = u & 7;
            float4 w = *(const float4*)&W1T[n * IN_DIM + kc * 64 + j * 8];
            *(float4*)&Bsm[n][j * 8] = w;
        }
        __syncthreads();
        #pragma unroll
        for (int ks = 0; ks < 2; ks++) {
            half8 a0 = *(const half8*)&Asm[wave * 32 + m16][ks * 32 + kq * 8];
            half8 a1 = *(const half8*)&Asm[wave * 32 + 16 + m16][ks * 32 + kq * 8];
            #pragma unroll
            for (int nt = 0; nt < 8; nt++) {
                half8 b = *(const half8*)&Bsm[nt * 16 + m16][ks * 32 + kq * 8];
                acc[0][nt] = __builtin_amdgcn_mfma_f32_16x16x32_f16(a0, b, acc[0][nt], 0, 0, 0);
                acc[1][nt] = __builtin_amdgcn_mfma_f32_16x16x32_f16(a1, b, acc[1][nt], 0, 0, 0);
            }
        }
        __syncthreads();
    }
    #pragma unroll
    for (int mt = 0; mt < 2; mt++) {
        const int gr0 = row0 + wave * 32 + mt * 16 + kq * 4;
        float dv[4];
        #pragma unroll
        for (int r = 0; r < 4; r++)
            dv[r] = (gr0 + r < N_NODES) ? dinv[gr0 + r] : 0.f;
        #pragma unroll
        for (int nt = 0; nt < 8; nt++) {
            int c = nt * 16 + m16;
            #pragma unroll
            for (int r = 0; r < 4; r++) {
                if (gr0 + r < N_NODES)
                    H1s[(long)(gr0 + r) * HIDDEN + c] = __float2half_rn(acc[mt][nt][r] * dv[r]);
            }
        }
    }
}

// ---------------- k_build: histogram -> prefix -> row_ptr -> scatter ----------------
// (dinv computed earlier by k_dinv; H1 rows pre-scaled at GEMM1 write)

__global__ __launch_bounds__(256) void k_build(const int* __restrict__ bfill,
                                               const unsigned long long* __restrict__ bpair,
                                               int* __restrict__ row_ptr,
                                               int* __restrict__ col) {
    __shared__ int h[NPB];
    __shared__ int pfx[NPB];
    __shared__ int sred[4];
    const int b  = blockIdx.x;
    const int nb = b * NPB;
    const int nn = min(NPB, N_NODES - nb);
    const int t  = threadIdx.x;
    int v = (t < b) ? bfill[t] : 0;
    #pragma unroll
    for (int dl = 32; dl > 0; dl >>= 1) v += __shfl_down(v, dl, 64);
    if ((t & 63) == 0) sred[t >> 6] = v;
    for (int i = t; i < NPB; i += 256) h[i] = 0;
    __syncthreads();
    const int base_b = sred[0] + sred[1] + sred[2] + sred[3];
    const int n = bfill[b];
    for (int i = t; i < n; i += 256) {
        int dd = (int)(bpair[(long)b * BCAP + i] >> 32);
        atomicAdd(&h[dd - nb], 1);
    }
    __syncthreads();
    if (t < 64) {   // wave 0: exclusive scan of degrees
        int carry = 0;
        #pragma unroll
        for (int c = 0; c < (NPB + 63) / 64; c++) {
            int idx = c * 64 + t;
            int hv = (idx < nn) ? h[idx] : 0;
            int s = hv;
            #pragma unroll
            for (int d2 = 1; d2 < 64; d2 <<= 1) {
                int u = __shfl_up(s, d2, 64);
                if (t >= d2) s += u;
            }
            if (idx < nn) {
                int ex = base_b + carry + (s - hv);
                pfx[idx] = ex;
                row_ptr[nb + idx] = ex;
            }
            carry += __shfl(s, 63, 64);
        }
    }
    __syncthreads();
    for (int i = t; i < nn; i += 256) h[i] = 0;   // reuse as fill counters
    __syncthreads();
    for (int i = t; i < n; i += 256) {
        unsigned long long p = bpair[(long)b * BCAP + i];
        int dd = (int)(p >> 32);
        int ss = (int)(p & 0xFFFFFFFFu);
        int pos = pfx[dd - nb] + atomicAdd(&h[dd - nb], 1);
        col[pos] = ss;
    }
    if (b == 0 && t == 0) row_ptr[N_NODES] = N_EDGES;
}

// ---------------- k_agg1g2: Agg1 (+bias+ReLU, pre-scale) + MFMA GEMM2 -> H2s fp16 ----------------
// Round-0 structure: block = 16 nodes, each wave serially aggregates 4 nodes with a
// full-row gather per edge (64 lanes x half2 = 256B). e0/e1 forced to SGPR via
// readfirstlane so col[e..] stay scalar loads (SMEM pipe). Edge loop unrolled 8 for
// 8 gathers in flight per wave (round-0 had 4 — latency-bound per the counters).

__global__ __launch_bounds__(256) void k_agg1g2(const __half* __restrict__ H1s,
                                                const int* __restrict__ row_ptr,
                                                const int* __restrict__ col,
                                                const float* __restrict__ dinv,
                                                const float* __restrict__ b1,
                                                const __half* __restrict__ W2T,
                                                __half* __restrict__ H2s) {
    __shared__ __align__(16) _Float16 rows[16][136];   // +8 pad: 16B-aligned, 2-way-max banks
    const int wave = threadIdx.x >> 6;
    const int lane = threadIdx.x & 63;
    const __half2* base = (const __half2*)H1s;   // row stride 64 half2
    const float2 bb = ((const float2*)b1)[lane];
    const int d00 = blockIdx.x * 16 + wave * 4;

    #pragma unroll
    for (int i = 0; i < 4; i++) {
        const int d = d00 + i;
        const int e0 = __builtin_amdgcn_readfirstlane(row_ptr[d]);
        const int e1 = __builtin_amdgcn_readfirstlane(row_ptr[d + 1]);
        float ax = 0.f, ay = 0.f;
        int e = e0;
        for (; e + 7 < e1; e += 8) {
            int s0 = col[e],     s1 = col[e + 1], s2 = col[e + 2], s3 = col[e + 3];
            int s4 = col[e + 4], s5 = col[e + 5], s6 = col[e + 6], s7 = col[e + 7];
            float2 f0 = __half22float2(base[(long)s0 * 64 + lane]);
            float2 f1 = __half22float2(base[(long)s1 * 64 + lane]);
            float2 f2 = __half22float2(base[(long)s2 * 64 + lane]);
            float2 f3 = __half22float2(base[(long)s3 * 64 + lane]);
            float2 f4 = __half22float2(base[(long)s4 * 64 + lane]);
            float2 f5 = __half22float2(base[(long)s5 * 64 + lane]);
            float2 f6 = __half22float2(base[(long)s6 * 64 + lane]);
            float2 f7 = __half22float2(base[(long)s7 * 64 + lane]);
            ax += ((f0.x + f1.x) + (f2.x + f3.x)) + ((f4.x + f5.x) + (f6.x + f7.x));
            ay += ((f0.y + f1.y) + (f2.y + f3.y)) + ((f4.y + f5.y) + (f6.y + f7.y));
        }
        for (; e + 3 < e1; e += 4) {
            int s0 = col[e], s1 = col[e + 1], s2 = col[e + 2], s3 = col[e + 3];
            float2 f0 = __half22float2(base[(long)s0 * 64 + lane]);
            float2 f1 = __half22float2(base[(long)s1 * 64 + lane]);
            float2 f2 = __half22float2(base[(long)s2 * 64 + lane]);
            float2 f3 = __half22float2(base[(long)s3 * 64 + lane]);
            ax += (f0.x + f1.x) + (f2.x + f3.x);
            ay += (f0.y + f1.y) + (f2.y + f3.y);
        }
        for (; e < e1; e++) {
            float2 f = __half22float2(base[(long)col[e] * 64 + lane]);
            ax += f.x; ay += f.y;
        }
        float2 fs = __half22float2(base[(long)d * 64 + lane]);   // self-loop (pre-scaled)
        ax += fs.x; ay += fs.y;
        const float dd = dinv[d];
        // pre-scale the relu row by dd so the MFMA needs no post-scale
        float ox = fmaxf(dd * ax + bb.x, 0.f) * dd;
        float oy = fmaxf(dd * ay + bb.y, 0.f) * dd;
        *(__half2*)&rows[wave * 4 + i][lane * 2] =
            __halves2half2(__float2half_rn(ox), __float2half_rn(oy));
    }
    __syncthreads();

    if (wave < 3) {   // 3 n-tiles of 16 cols (48 padded, 40 real)
        const int m16 = lane & 15;
        const int kq  = lane >> 4;
        floatx4 acc = (floatx4)0.f;
        #pragma unroll
        for (int ks = 0; ks < 4; ks++) {
            half8 a = *(const half8*)&rows[m16][ks * 32 + kq * 8];
            half8 b = *(const half8*)&W2T[(wave * 16 + m16) * HIDDEN + ks * 32 + kq * 8];
            acc = __builtin_amdgcn_mfma_f32_16x16x32_f16(a, b, acc, 0, 0, 0);
        }
        const int c = wave * 16 + m16;
        if (c < NCLS) {
            const int gr0 = blockIdx.x * 16 + kq * 4;
            #pragma unroll
            for (int r = 0; r < 4; r++)
                H2s[(long)(gr0 + r) * NCLS + c] = __float2half_rn(acc[r]);
        }
    }
}

// ---------------- Aggregation 2 (+bias) -> fp32 out. 6 nodes x 10 half4-lanes per wave ----------------

__global__ __launch_bounds__(256) void k_agg2(const __half* __restrict__ H2s,
                                              const int* __restrict__ row_ptr,
                                              const int* __restrict__ col,
                                              const float* __restrict__ dinv,
                                              const float* __restrict__ b2,
                                              float* __restrict__ out) {
    const int wave = threadIdx.x >> 6;
    const int lane = threadIdx.x & 63;
    const int g = lane / 10;              // 0..5 active, lanes 60-63 idle
    const int f = lane - g * 10;          // 0..9 -> feats 4f..4f+3
    const int d = blockIdx.x * 24 + wave * 6 + g;
    const bool act = (g < 6) && (d < N_NODES);
    int e0 = 0, e1 = 0;
    if (act) { e0 = row_ptr[d]; e1 = row_ptr[d + 1]; }
    const half4f* base4 = (const half4f*)H2s;   // row stride 10 half4
    float s0 = 0.f, s1 = 0.f, s2 = 0.f, s3 = 0.f;
    int e = e0;
    while (__any(e < e1)) {
        #pragma unroll
        for (int u = 0; u < 4; u++) {
            if (e + u < e1) {
                half4f v = base4[(long)col[e + u] * 10 + f];
                s0 += (float)v[0]; s1 += (float)v[1]; s2 += (float)v[2]; s3 += (float)v[3];
            }
        }
        e += 4;
    }
    if (act) {
        half4f v = base4[(long)d * 10 + f];   // self-loop (pre-scaled)
        s0 += (float)v[0]; s1 += (float)v[1]; s2 += (float)v[2]; s3 += (float)v[3];
        float dd = dinv[d];
        float4 bbv = ((const float4*)b2)[f];
        float4 o = make_float4(dd * s0 + bbv.x, dd * s1 + bbv.y, dd * s2 + bbv.z, dd * s3 + bbv.w);
        ((float4*)out)[(long)d * 10 + f] = o;
    }
}

// ---------------- launch ----------------

extern "C" void kernel_launch(void* const* d_in, const int* in_sizes, int n_in,
                              void* d_out, int out_size, void* d_ws, size_t ws_size,
                              hipStream_t stream) {
    const float* x  = (const float*)d_in[0];
    const int*   ei = (const int*)d_in[1];
    const float* W1 = (const float*)d_in[2];
    const float* b1 = (const float*)d_in[3];
    const float* W2 = (const float*)d_in[4];
    const float* b2 = (const float*)d_in[5];
    const int* srcE = ei;
    const int* dstE = ei + N_EDGES;

    int*   row_ptr = (int*)d_ws;                    // 100032 ints
    int*   bfill   = row_ptr + 100032;              // 256
    int*   col     = bfill + 256;                   // 1600000
    float* dinv    = (float*)(col + N_EDGES);       // 100032 floats
    __half* H1s    = (__half*)(dinv + 100032);      // 12.8M halfs (25.6 MB)
    __half* H2s    = H1s + (long)N_NODES * HIDDEN;  // 4M halfs (8 MB)
    __half* W1T    = H2s + (long)N_NODES * NCLS;    // 32768 halfs
    __half* W2T    = W1T + IN_DIM * HIDDEN;         // 6144 halfs
    unsigned long long* bpair = (unsigned long long*)(W2T + NCLS_PAD * HIDDEN);  // 2.1M (16.8 MB)
    int*   deg     = (int*)bpair;                   // aliases bpair: deg dead before bpair written

    k_prep   <<<521, 256, 0, stream>>>(W1, W1T, W2, W2T, bfill, deg);
    k_deg    <<<782, 256, 0, stream>>>(dstE, deg);
    k_dinv   <<<391, 256, 0, stream>>>(deg, dinv);
    k_binmm  <<<BIN_BLOCKS + GEMM1_BLOCKS, 256, 0, stream>>>(srcE, dstE, bfill, bpair, x, W1T, dinv, H1s);
    k_build  <<<N_BUCKETS, 256, 0, stream>>>(bfill, bpair, row_ptr, col);
    k_agg1g2 <<<N_NODES / 16, 256, 0, stream>>>(H1s, row_ptr, col, dinv, b1, W2T, H2s);
    k_agg2   <<<(N_NODES + 23) / 24, 256, 0, stream>>>(H2s, row_ptr, col, dinv, b2, (float*)d_out);
}

// Round 3
// 337.913 us; speedup vs baseline: 1.2033x; 1.2033x over previous
//
#include <hip/hip_runtime.h>
#include <hip/hip_bf16.h>
#include <hip/hip_fp16.h>

#define N_NODES 100000
#define N_EDGES 1600000
#define IN_DIM 256
#define HIDDEN 128
#define NCLS 40
#define NCLS_PAD 48      // padded to 3 MFMA n-tiles

#define N_BUCKETS 256
#define NPB 391          // nodes per bucket = ceil(100000/256)
#define BCAP 8192        // bucket capacity (mean 6256, +24 sigma)
#define EPT 16           // edges per thread in bin phase
#define BIN_WG 4096      // edges per workgroup (256*16)
#define BIN_BLOCKS 391   // ceil(N_EDGES / BIN_WG)
#define GEMM1_BLOCKS 782 // ceil(N_NODES / 128)

typedef __attribute__((ext_vector_type(8))) _Float16 half8;
typedef __attribute__((ext_vector_type(4))) _Float16 half4f;
typedef __attribute__((ext_vector_type(4))) float floatx4;

// ---------------- k_prep: W1T / W2T fp16 transposes + bfill zero ----------------

__global__ __launch_bounds__(256) void k_prep(const float* __restrict__ W1, __half* __restrict__ W1T,
                                              const float* __restrict__ W2, __half* __restrict__ W2T,
                                              int* __restrict__ bfill) {
    const int t = threadIdx.x;
    if (blockIdx.x < 128) {              // W1T: [n][k] fp16, 128 x 256
        int i = blockIdx.x * 256 + t;
        int k = i >> 7, n = i & 127;
        W1T[n * IN_DIM + k] = __float2half_rn(W1[i]);
    } else if (blockIdx.x == 128) {      // W2T: [n][k] fp16, 48 x 128, zero-pad n>=40
        for (int i = t; i < NCLS_PAD * HIDDEN; i += 256) {
            int n = i >> 7, k = i & 127;
            W2T[n * HIDDEN + k] = (n < NCLS) ? __float2half_rn(W2[k * NCLS + n]) : __float2half_rn(0.f);
        }
    } else {
        bfill[t] = 0;
    }
}

// ---------------- k_binmm: [0,391) LDS-staged edge binning  ∥  [391,1173) GEMM1 (unscaled) ----------------
// GEMM phase uses A-tile register prefetch: next kc's X loads are issued right after
// the post-store barrier, so HBM latency hides under the MFMA block (wait lands at the
// next iteration's LDS store).

__global__ __launch_bounds__(256) void k_binmm(const int* __restrict__ src, const int* __restrict__ dst,
                                               int* __restrict__ bfill,
                                               unsigned long long* __restrict__ bpair,
                                               const float* __restrict__ X,
                                               const __half* __restrict__ W1T,
                                               __half* __restrict__ H1s) {
    __shared__ __align__(16) char smraw[39936];   // union: bin(39936) / gemm1(36864)
    const int t = threadIdx.x;

    if (blockIdx.x < BIN_BLOCKS) {
        // ---- bin phase ----
        int* hist   = (int*)smraw;                               // 256
        int* bstart = hist + 256;                                // 256
        int* gbase  = bstart + 256;                              // 256
        unsigned long long* stage = (unsigned long long*)(smraw + 3072);   // 4096 (32 KB)
        unsigned char* bid = (unsigned char*)(smraw + 3072 + 32768);       // 4096
        hist[t] = 0;
        __syncthreads();
        const long e0 = (long)blockIdx.x * BIN_WG;
        const int n_valid = (int)min((long)BIN_WG, (long)N_EDGES - e0);
        int msrc[EPT], mdst[EPT], moff[EPT];
        #pragma unroll
        for (int i = 0; i < EPT; i++) {
            long e = e0 + t + i * 256;
            if (e < N_EDGES) {
                msrc[i] = src[e];
                mdst[i] = dst[e];
                moff[i] = atomicAdd(&hist[mdst[i] / NPB], 1);
            } else {
                mdst[i] = -1;
            }
        }
        __syncthreads();
        if (t < 64) {   // wave 0: exclusive scan of hist[256]
            int carry = 0;
            #pragma unroll
            for (int c = 0; c < 4; c++) {
                int idx = c * 64 + t;
                int hv = hist[idx];
                int s = hv;
                #pragma unroll
                for (int d2 = 1; d2 < 64; d2 <<= 1) {
                    int u = __shfl_up(s, d2, 64);
                    if (t >= d2) s += u;
                }
                bstart[idx] = carry + (s - hv);
                carry += __shfl(s, 63, 64);
            }
        }
        __syncthreads();
        int h = hist[t];
        gbase[t] = (h > 0) ? atomicAdd(&bfill[t], h) : 0;
        #pragma unroll
        for (int i = 0; i < EPT; i++) {
            if (mdst[i] >= 0) {
                int b = mdst[i] / NPB;
                int pos = bstart[b] + moff[i];
                stage[pos] = ((unsigned long long)(unsigned)mdst[i] << 32) | (unsigned)msrc[i];
                bid[pos] = (unsigned char)b;
            }
        }
        __syncthreads();
        for (int i = t; i < n_valid; i += 256) {
            int b = bid[i];
            int dest = gbase[b] + (i - bstart[b]);
            bpair[(long)b * BCAP + dest] = stage[i];
        }
        return;
    }

    // ---- gemm1 phase (128x128 tile, MFMA f16, unscaled output) ----
    _Float16 (*Asm)[72] = (_Float16(*)[72])smraw;
    _Float16 (*Bsm)[72] = (_Float16(*)[72])(smraw + 128 * 72 * 2);
    const int wave = t >> 6;
    const int lane = t & 63;
    const int m16  = lane & 15;
    const int kq   = lane >> 4;
    const int row0 = (blockIdx.x - BIN_BLOCKS) * 128;

    floatx4 acc[2][8];
    #pragma unroll
    for (int mt = 0; mt < 2; mt++)
        #pragma unroll
        for (int i = 0; i < 8; i++) acc[mt][i] = (floatx4)0.f;

    float4 ar[4][2];   // A-tile prefetch registers (32B/thread)
    auto loadA = [&](int kcL) {
        #pragma unroll
        for (int it = 0; it < 4; it++) {
            int u = t + it * 256;
            int r = u >> 3, j = u & 7;
            int gr = row0 + r;
            if (gr < N_NODES) {
                const float* p = &X[(long)gr * IN_DIM + kcL * 64 + j * 8];
                ar[it][0] = *(const float4*)p;
                ar[it][1] = *(const float4*)(p + 4);
            } else {
                ar[it][0] = make_float4(0.f, 0.f, 0.f, 0.f);
                ar[it][1] = make_float4(0.f, 0.f, 0.f, 0.f);
            }
        }
    };

    loadA(0);
    for (int kc = 0; kc < 4; kc++) {
        // store prefetched A (cvt fp32->fp16), stage B (L2-hot W1T)
        #pragma unroll
        for (int it = 0; it < 4; it++) {
            int u = t + it * 256;
            int r = u >> 3, j = u & 7;
            half8 hh;
            hh[0] = (_Float16)ar[it][0].x; hh[1] = (_Float16)ar[it][0].y;
            hh[2] = (_Float16)ar[it][0].z; hh[3] = (_Float16)ar[it][0].w;
            hh[4] = (_Float16)ar[it][1].x; hh[5] = (_Float16)ar[it][1].y;
            hh[6] = (_Float16)ar[it][1].z; hh[7] = (_Float16)ar[it][1].w;
            *(half8*)&Asm[r][j * 8] = hh;
        }
        #pragma unroll
        for (int it = 0; it < 4; it++) {
            int u = t + it * 256;
            int n = u >> 3, j = u & 7;
            float4 w = *(const float4*)&W1T[n * IN_DIM + kc * 64 + j * 8];
            *(float4*)&Bsm[n][j * 8] = w;
        }
        __syncthreads();
        if (kc < 3) loadA(kc + 1);    // issue next-chunk loads; latency hides under MFMA
        #pragma unroll
        for (int ks = 0; ks < 2; ks++) {
            half8 a0 = *(const half8*)&Asm[wave * 32 + m16][ks * 32 + kq * 8];
            half8 a1 = *(const half8*)&Asm[wave * 32 + 16 + m16][ks * 32 + kq * 8];
            #pragma unroll
            for (int nt = 0; nt < 8; nt++) {
                half8 b = *(const half8*)&Bsm[nt * 16 + m16][ks * 32 + kq * 8];
                acc[0][nt] = __builtin_amdgcn_mfma_f32_16x16x32_f16(a0, b, acc[0][nt], 0, 0, 0);
                acc[1][nt] = __builtin_amdgcn_mfma_f32_16x16x32_f16(a1, b, acc[1][nt], 0, 0, 0);
            }
        }
        __syncthreads();
    }
    #pragma unroll
    for (int mt = 0; mt < 2; mt++) {
        const int gr0 = row0 + wave * 32 + mt * 16 + kq * 4;
        #pragma unroll
        for (int nt = 0; nt < 8; nt++) {
            int c = nt * 16 + m16;
            #pragma unroll
            for (int r = 0; r < 4; r++) {
                if (gr0 + r < N_NODES)
                    H1s[(long)(gr0 + r) * HIDDEN + c] = __float2half_rn(acc[mt][nt][r]);
            }
        }
    }
}

// ---------------- k_build: histogram -> prefix -> row_ptr/dinv -> scatter ----------------
// (no H1 scaling: dinv[src] folds into k_agg1g2 via SCALAR loads)

__global__ __launch_bounds__(256) void k_build(const int* __restrict__ bfill,
                                               const unsigned long long* __restrict__ bpair,
                                               int* __restrict__ row_ptr, float* __restrict__ dinv,
                                               int* __restrict__ col) {
    __shared__ int h[NPB];
    __shared__ int pfx[NPB];
    __shared__ int sred[4];
    const int b  = blockIdx.x;
    const int nb = b * NPB;
    const int nn = min(NPB, N_NODES - nb);
    const int t  = threadIdx.x;
    int v = (t < b) ? bfill[t] : 0;
    #pragma unroll
    for (int dl = 32; dl > 0; dl >>= 1) v += __shfl_down(v, dl, 64);
    if ((t & 63) == 0) sred[t >> 6] = v;
    for (int i = t; i < NPB; i += 256) h[i] = 0;
    __syncthreads();
    const int base_b = sred[0] + sred[1] + sred[2] + sred[3];
    const int n = bfill[b];
    for (int i = t; i < n; i += 256) {
        int dd = (int)(bpair[(long)b * BCAP + i] >> 32);
        atomicAdd(&h[dd - nb], 1);
    }
    __syncthreads();
    if (t < 64) {   // wave 0: exclusive scan of degrees
        int carry = 0;
        #pragma unroll
        for (int c = 0; c < (NPB + 63) / 64; c++) {
            int idx = c * 64 + t;
            int hv = (idx < nn) ? h[idx] : 0;
            int s = hv;
            #pragma unroll
            for (int d2 = 1; d2 < 64; d2 <<= 1) {
                int u = __shfl_up(s, d2, 64);
                if (t >= d2) s += u;
            }
            if (idx < nn) {
                int ex = base_b + carry + (s - hv);
                pfx[idx] = ex;
                row_ptr[nb + idx] = ex;
                dinv[nb + idx] = rsqrtf((float)(hv + 1));   // +1 self-loop
            }
            carry += __shfl(s, 63, 64);
        }
    }
    __syncthreads();
    for (int i = t; i < nn; i += 256) h[i] = 0;   // reuse as fill counters
    __syncthreads();
    for (int i = t; i < n; i += 256) {
        unsigned long long p = bpair[(long)b * BCAP + i];
        int dd = (int)(p >> 32);
        int ss = (int)(p & 0xFFFFFFFFu);
        int pos = pfx[dd - nb] + atomicAdd(&h[dd - nb], 1);
        col[pos] = ss;
    }
    if (b == 0 && t == 0) row_ptr[N_NODES] = N_EDGES;
}

// ---------------- k_agg1g2: Agg1 (+bias+ReLU, pre-scale) + MFMA GEMM2 -> H2s fp16 ----------------
// Block = 16 nodes, each wave serially aggregates 4 nodes with a full-row gather per
// edge (64 lanes x half2 = 256B). e0/e1 forced to SGPR via readfirstlane so col[e..]
// are SGPR scalar loads; therefore dinv[col[e]] are ALSO uniform-address scalar loads
// (SMEM pipe, overlapped with the VMEM gathers) and the sym-norm scale folds into the
// accumulate as fmac-with-SGPR — no separate H1-scale pass anywhere. 8 gathers in flight.

__global__ __launch_bounds__(256) void k_agg1g2(const __half* __restrict__ H1s,
                                                const int* __restrict__ row_ptr,
                                                const int* __restrict__ col,
                                                const float* __restrict__ dinv,
                                                const float* __restrict__ b1,
                                                const __half* __restrict__ W2T,
                                                __half* __restrict__ H2s) {
    __shared__ __align__(16) _Float16 rows[16][136];   // +8 pad: 16B-aligned, 2-way-max banks
    const int wave = threadIdx.x >> 6;
    const int lane = threadIdx.x & 63;
    const __half2* base = (const __half2*)H1s;   // row stride 64 half2
    const float2 bb = ((const float2*)b1)[lane];
    const int d00 = blockIdx.x * 16 + wave * 4;

    #pragma unroll
    for (int i = 0; i < 4; i++) {
        const int d = d00 + i;
        const int e0 = __builtin_amdgcn_readfirstlane(row_ptr[d]);
        const int e1 = __builtin_amdgcn_readfirstlane(row_ptr[d + 1]);
        const float dd = dinv[d];
        float ax = 0.f, ay = 0.f;
        int e = e0;
        for (; e + 7 < e1; e += 8) {
            int s0 = col[e],     s1 = col[e + 1], s2 = col[e + 2], s3 = col[e + 3];
            int s4 = col[e + 4], s5 = col[e + 5], s6 = col[e + 6], s7 = col[e + 7];
            float d0 = dinv[s0], d1 = dinv[s1], d2 = dinv[s2], d3 = dinv[s3];
            float d4 = dinv[s4], d5 = dinv[s5], d6 = dinv[s6], d7 = dinv[s7];
            float2 f0 = __half22float2(base[(long)s0 * 64 + lane]);
            float2 f1 = __half22float2(base[(long)s1 * 64 + lane]);
            float2 f2 = __half22float2(base[(long)s2 * 64 + lane]);
            float2 f3 = __half22float2(base[(long)s3 * 64 + lane]);
            float2 f4 = __half22float2(base[(long)s4 * 64 + lane]);
            float2 f5 = __half22float2(base[(long)s5 * 64 + lane]);
            float2 f6 = __half22float2(base[(long)s6 * 64 + lane]);
            float2 f7 = __half22float2(base[(long)s7 * 64 + lane]);
            ax += d0 * f0.x + d1 * f1.x + d2 * f2.x + d3 * f3.x
                + d4 * f4.x + d5 * f5.x + d6 * f6.x + d7 * f7.x;
            ay += d0 * f0.y + d1 * f1.y + d2 * f2.y + d3 * f3.y
                + d4 * f4.y + d5 * f5.y + d6 * f6.y + d7 * f7.y;
        }
        for (; e + 3 < e1; e += 4) {
            int s0 = col[e], s1 = col[e + 1], s2 = col[e + 2], s3 = col[e + 3];
            float d0 = dinv[s0], d1 = dinv[s1], d2 = dinv[s2], d3 = dinv[s3];
            float2 f0 = __half22float2(base[(long)s0 * 64 + lane]);
            float2 f1 = __half22float2(base[(long)s1 * 64 + lane]);
            float2 f2 = __half22float2(base[(long)s2 * 64 + lane]);
            float2 f3 = __half22float2(base[(long)s3 * 64 + lane]);
            ax += d0 * f0.x + d1 * f1.x + d2 * f2.x + d3 * f3.x;
            ay += d0 * f0.y + d1 * f1.y + d2 * f2.y + d3 * f3.y;
        }
        for (; e < e1; e++) {
            int s = col[e];
            float dv = dinv[s];
            float2 f = __half22float2(base[(long)s * 64 + lane]);
            ax += dv * f.x; ay += dv * f.y;
        }
        // self-loop (unscaled H1 row x dd)
        float2 fs = __half22float2(base[(long)d * 64 + lane]);
        ax += dd * fs.x; ay += dd * fs.y;
        // bias + relu, then pre-scale by dd so the layer-2 MFMA needs no post-scale
        float ox = fmaxf(dd * ax + bb.x, 0.f) * dd;
        float oy = fmaxf(dd * ay + bb.y, 0.f) * dd;
        *(__half2*)&rows[wave * 4 + i][lane * 2] =
            __halves2half2(__float2half_rn(ox), __float2half_rn(oy));
    }
    __syncthreads();

    if (wave < 3) {   // 3 n-tiles of 16 cols (48 padded, 40 real)
        const int m16 = lane & 15;
        const int kq  = lane >> 4;
        floatx4 acc = (floatx4)0.f;
        #pragma unroll
        for (int ks = 0; ks < 4; ks++) {
            half8 a = *(const half8*)&rows[m16][ks * 32 + kq * 8];
            half8 b = *(const half8*)&W2T[(wave * 16 + m16) * HIDDEN + ks * 32 + kq * 8];
            acc = __builtin_amdgcn_mfma_f32_16x16x32_f16(a, b, acc, 0, 0, 0);
        }
        const int c = wave * 16 + m16;
        if (c < NCLS) {
            const int gr0 = blockIdx.x * 16 + kq * 4;
            #pragma unroll
            for (int r = 0; r < 4; r++)
                H2s[(long)(gr0 + r) * NCLS + c] = __float2half_rn(acc[r]);
        }
    }
}

// ---------------- Aggregation 2 (+bias) -> fp32 out. 6 nodes x 10 half4-lanes per wave ----------------

__global__ __launch_bounds__(256) void k_agg2(const __half* __restrict__ H2s,
                                              const int* __restrict__ row_ptr,
                                              const int* __restrict__ col,
                                              const float* __restrict__ dinv,
                                              const float* __restrict__ b2,
                                              float* __restrict__ out) {
    const int wave = threadIdx.x >> 6;
    const int lane = threadIdx.x & 63;
    const int g = lane / 10;              // 0..5 active, lanes 60-63 idle
    const int f = lane - g * 10;          // 0..9 -> feats 4f..4f+3
    const int d = blockIdx.x * 24 + wave * 6 + g;
    const bool act = (g < 6) && (d < N_NODES);
    int e0 = 0, e1 = 0;
    if (act) { e0 = row_ptr[d]; e1 = row_ptr[d + 1]; }
    const half4f* base4 = (const half4f*)H2s;   // row stride 10 half4
    float s0 = 0.f, s1 = 0.f, s2 = 0.f, s3 = 0.f;
    int e = e0;
    while (__any(e < e1)) {
        #pragma unroll
        for (int u = 0; u < 4; u++) {
            if (e + u < e1) {
                half4f v = base4[(long)col[e + u] * 10 + f];
                s0 += (float)v[0]; s1 += (float)v[1]; s2 += (float)v[2]; s3 += (float)v[3];
            }
        }
        e += 4;
    }
    if (act) {
        half4f v = base4[(long)d * 10 + f];   // self-loop (pre-scaled)
        s0 += (float)v[0]; s1 += (float)v[1]; s2 += (float)v[2]; s3 += (float)v[3];
        float dd = dinv[d];
        float4 bbv = ((const float4*)b2)[f];
        float4 o = make_float4(dd * s0 + bbv.x, dd * s1 + bbv.y, dd * s2 + bbv.z, dd * s3 + bbv.w);
        ((float4*)out)[(long)d * 10 + f] = o;
    }
}

// ---------------- launch ----------------

extern "C" void kernel_launch(void* const* d_in, const int* in_sizes, int n_in,
                              void* d_out, int out_size, void* d_ws, size_t ws_size,
                              hipStream_t stream) {
    const float* x  = (const float*)d_in[0];
    const int*   ei = (const int*)d_in[1];
    const float* W1 = (const float*)d_in[2];
    const float* b1 = (const float*)d_in[3];
    const float* W2 = (const float*)d_in[4];
    const float* b2 = (const float*)d_in[5];
    const int* srcE = ei;
    const int* dstE = ei + N_EDGES;

    int*   row_ptr = (int*)d_ws;                    // 100032 ints
    int*   bfill   = row_ptr + 100032;              // 256
    int*   col     = bfill + 256;                   // 1600000
    float* dinv    = (float*)(col + N_EDGES);       // 100032 floats
    __half* H1s    = (__half*)(dinv + 100032);      // 12.8M halfs (25.6 MB)
    __half* H2s    = H1s + (long)N_NODES * HIDDEN;  // 4M halfs (8 MB)
    __half* W1T    = H2s + (long)N_NODES * NCLS;    // 32768 halfs
    __half* W2T    = W1T + IN_DIM * HIDDEN;         // 6144 halfs
    unsigned long long* bpair = (unsigned long long*)(W2T + NCLS_PAD * HIDDEN);  // 2.1M (16.8 MB)

    k_prep   <<<130, 256, 0, stream>>>(W1, W1T, W2, W2T, bfill);
    k_binmm  <<<BIN_BLOCKS + GEMM1_BLOCKS, 256, 0, stream>>>(srcE, dstE, bfill, bpair, x, W1T, H1s);
    k_build  <<<N_BUCKETS, 256, 0, stream>>>(bfill, bpair, row_ptr, dinv, col);
    k_agg1g2 <<<N_NODES / 16, 256, 0, stream>>>(H1s, row_ptr, col, dinv, b1, W2T, H2s);
    k_agg2   <<<(N_NODES + 23) / 24, 256, 0, stream>>>(H2s, row_ptr, col, dinv, b2, (float*)d_out);
}